// Round 5
// baseline (419.417 us; speedup 1.0000x reference)
//
#include <hip/hip_runtime.h>

#define BB 4096
#define TT 64
#define NH 60
#define KF 7680   // T * 2H
#define NC 600

typedef short bf16x8 __attribute__((ext_vector_type(8)));
typedef float f32x4 __attribute__((ext_vector_type(4)));
#define MFMA16(A,B,C) __builtin_amdgcn_mfma_f32_16x16x32_bf16(A,B,C,0,0,0)

typedef const __attribute__((address_space(1))) unsigned int* gas_u32;
typedef __attribute__((address_space(3))) unsigned int* las_u32;

__device__ __forceinline__ unsigned short f2bf(float v) {
    unsigned int u = __float_as_uint(v);
    return (unsigned short)((u + 0x7FFFu + ((u >> 16) & 1u)) >> 16);   // RNE fp32->bf16
}
__device__ __forceinline__ float bf2f(unsigned short b) {
    return __uint_as_float(((unsigned int)b) << 16);
}
__device__ __forceinline__ float sigf(float v)     { return 1.f / (1.f + __expf(-v)); }
__device__ __forceinline__ float tanhfast(float v) { return 2.f / (1.f + __expf(-2.f * v)) - 1.f; }

// unpack 8 packed (hi<<16|lo) u32 -> hi bf16x8, lo bf16x8
__device__ __forceinline__ void unpk(const uint4 a, const uint4 b, bf16x8& hi, bf16x8& lo) {
    uint4 h, l;
    h.x = (a.x >> 16) | (a.y & 0xFFFF0000u);
    h.y = (a.z >> 16) | (a.w & 0xFFFF0000u);
    h.z = (b.x >> 16) | (b.y & 0xFFFF0000u);
    h.w = (b.z >> 16) | (b.w & 0xFFFF0000u);
    l.x = (a.x & 0xFFFFu) | (a.y << 16);
    l.y = (a.z & 0xFFFFu) | (a.w << 16);
    l.z = (b.x & 0xFFFFu) | (b.y << 16);
    l.w = (b.z & 0xFFFFu) | (b.w << 16);
    hi = __builtin_bit_cast(bf16x8, h);
    lo = __builtin_bit_cast(bf16x8, l);
}

// ---------------------------------------------------------------------------
// GRU round-5: 16 rows x 1 dir per block, 256 thr = 4 waves (1 mtile x 4 ug).
// Grid 512 -> 2 independent blocks/CU (decoupled barriers = latency overlap).
// Numerics identical to gru4 (3-term split, same gate order).
// ---------------------------------------------------------------------------
__global__ __launch_bounds__(256, 2) void gru5_kernel(
    const float* __restrict__ x,      // [B][T][60]
    const float* __restrict__ w_ih,   // [2][180][60]
    const float* __restrict__ w_hh,   // [2][180][60]
    const float* __restrict__ b_ih,   // [2][180]
    const float* __restrict__ b_hh,   // [2][180]
    unsigned int* __restrict__ hs)    // [B][KF] packed (hi<<16 | lo) bf16
{
    __shared__ unsigned short XHh[2][16 * 128];   // 8 KB
    __shared__ unsigned short XHl[2][16 * 128];   // 8 KB
    __shared__ unsigned int hstage[2][16][60];    // 7.7 KB

    const int tid = threadIdx.x;
    const int d  = blockIdx.y;
    const int b0 = blockIdx.x * 16;
    const int wave = tid >> 6, lane = tid & 63;
    const int ug = wave;                  // 4 waves = 4 unit groups, 1 mtile
    const int l15 = lane & 15, lq = lane >> 4;
    const int j = ug * 16 + l15;
    const bool jv = j < NH;
    const int m = l15;                    // A-frag row
    const int rbase = lq * 4;             // C rows base

    for (int i = tid; i < 2 * 16 * 128; i += 256) { (&XHh[0][0])[i] = 0; (&XHl[0][0])[i] = 0; }

    // ---- W frags in registers (hi/lo), one-time ----
    bf16x8 wHf[3][4], wLf[3][4];
#pragma unroll
    for (int g = 0; g < 3; ++g) {
#pragma unroll
        for (int kt = 0; kt < 4; ++kt) {
            bf16x8 h8, l8;
            const int kb = kt * 32 + lq * 8;
#pragma unroll
            for (int e = 0; e < 8; ++e) {
                const int k = kb + e;
                float v = 0.f;
                if (jv) {
                    if (k < 60)                    v = w_ih[(size_t)d * 10800 + (g * 60 + j) * 60 + k];
                    else if (k >= 64 && k < 124)   v = w_hh[(size_t)d * 10800 + (g * 60 + j) * 60 + (k - 64)];
                }
                const unsigned short hb = f2bf(v);
                const unsigned short lb = f2bf(v - bf2f(hb));
                h8[e] = (short)hb; l8[e] = (short)lb;
            }
            wHf[g][kt] = h8; wLf[g][kt] = l8;
        }
    }

    float bir = 0, biz = 0, bin = 0, bhr = 0, bhz = 0, bhn = 0;
    if (jv) {
        bir = b_ih[d * 180 + j]; biz = b_ih[d * 180 + 60 + j]; bin = b_ih[d * 180 + 120 + j];
        bhr = b_hh[d * 180 + j]; bhz = b_hh[d * 180 + 60 + j]; bhn = b_hh[d * 180 + 120 + j];
    }

    // cooperative x-stage / hs-store map: 240 active (16 rows x 15 float4)
    const bool xact = tid < 240;
    const int rowx = xact ? tid / 15 : 15;
    const int cx   = xact ? tid % 15 : 14;
    const float* xb = x + ((size_t)(b0 + rowx) * TT) * 60 + cx * 4;
    unsigned int* hsb = hs + (size_t)(b0 + rowx) * KF + d * 60 + cx * 4;

    __syncthreads();

    if (xact) {
        const int tt0 = d ? (TT - 1) : 0;
        const float4 v = *(const float4*)(xb + tt0 * 60);
        const float vv[4] = {v.x, v.y, v.z, v.w};
#pragma unroll
        for (int e = 0; e < 4; ++e) {
            const int k = cx * 4 + e;
            const int idx = rowx * 128 + (((k >> 3) ^ (rowx & 7)) << 3) + (k & 7);
            const unsigned short hb = f2bf(vv[e]);
            XHh[0][idx] = hb; XHl[0][idx] = f2bf(vv[e] - bf2f(hb));
        }
    }
    float hold[4] = {0.f, 0.f, 0.f, 0.f};
    __syncthreads();

#pragma unroll 1
    for (int s = 0; s < TT; ++s) {
        const int p = s & 1, pn = p ^ 1;
        const int tt = d ? (TT - 1 - s) : s;

        float4 xp = make_float4(0.f, 0.f, 0.f, 0.f);
        const bool morex = (s < TT - 1) && xact;
        if (morex) xp = *(const float4*)(xb + (d ? (TT - 2 - s) : (s + 1)) * 60);

        // ---- MFMA phase on buf p ----
        f32x4 aR0 = {0,0,0,0}, aR1 = {0,0,0,0}, aZ0 = {0,0,0,0}, aZ1 = {0,0,0,0},
              aNX = {0,0,0,0}, aNH_ = {0,0,0,0};
        const unsigned short* Xh = &XHh[p][0];
        const unsigned short* Xl = &XHl[p][0];
#pragma unroll
        for (int kt = 0; kt < 4; ++kt) {
            const int c = kt * 4 + lq;
            const int off = m * 128 + ((c ^ (m & 7)) << 3);
            const bf16x8 aH = *(const bf16x8*)(Xh + off);
            const bf16x8 aL = *(const bf16x8*)(Xl + off);
            if (kt < 2) {
                aR0 = MFMA16(aH, wHf[0][kt], aR0); aR0 = MFMA16(aH, wLf[0][kt], aR0); aR0 = MFMA16(aL, wHf[0][kt], aR0);
                aZ0 = MFMA16(aH, wHf[1][kt], aZ0); aZ0 = MFMA16(aH, wLf[1][kt], aZ0); aZ0 = MFMA16(aL, wHf[1][kt], aZ0);
                aNX = MFMA16(aH, wHf[2][kt], aNX); aNX = MFMA16(aH, wLf[2][kt], aNX); aNX = MFMA16(aL, wHf[2][kt], aNX);
            } else {
                aR1 = MFMA16(aH, wHf[0][kt], aR1); aR1 = MFMA16(aH, wLf[0][kt], aR1); aR1 = MFMA16(aL, wHf[0][kt], aR1);
                aZ1 = MFMA16(aH, wHf[1][kt], aZ1); aZ1 = MFMA16(aH, wLf[1][kt], aZ1); aZ1 = MFMA16(aL, wHf[1][kt], aZ1);
                aNH_ = MFMA16(aH, wHf[2][kt], aNH_); aNH_ = MFMA16(aH, wLf[2][kt], aNH_); aNH_ = MFMA16(aL, wHf[2][kt], aNH_);
            }
        }

        // ---- gates ----
        float hnew[4];
#pragma unroll
        for (int r = 0; r < 4; ++r) {
            const float rr = sigf(aR0[r] + aR1[r] + bir + bhr);
            const float zz = sigf(aZ0[r] + aZ1[r] + biz + bhz);
            const float nn = tanhfast(aNX[r] + bin + rr * (aNH_[r] + bhn));
            hnew[r] = (1.f - zz) * nn + zz * hold[r];
            hold[r] = hnew[r];
        }

        // ---- write h' and x(s+1) into buf pn; hstage[pn] ----
        if (jv) {
#pragma unroll
            for (int r = 0; r < 4; ++r) {
                const int rw = rbase + r;
                const int k = 64 + j;
                const int idx = rw * 128 + (((k >> 3) ^ (rw & 7)) << 3) + (k & 7);
                const unsigned short hb = f2bf(hnew[r]);
                const unsigned short lb = f2bf(hnew[r] - bf2f(hb));
                XHh[pn][idx] = hb; XHl[pn][idx] = lb;
                hstage[pn][rw][j] = ((unsigned int)hb << 16) | lb;
            }
        }
        if (morex) {
            const float vv[4] = {xp.x, xp.y, xp.z, xp.w};
#pragma unroll
            for (int e = 0; e < 4; ++e) {
                const int k = cx * 4 + e;
                const int idx = rowx * 128 + (((k >> 3) ^ (rowx & 7)) << 3) + (k & 7);
                const unsigned short hb = f2bf(vv[e]);
                XHh[pn][idx] = hb; XHl[pn][idx] = f2bf(vv[e] - bf2f(hb));
            }
        }
        __syncthreads();   // the only barrier per step

        if (xact) {
            const uint4 hv = *(const uint4*)&hstage[pn][rowx][cx * 4];
            *(uint4*)(hsb + (size_t)tt * 120) = hv;
        }
    }
}

// out[b][c] = fcb[c]  (bias init; FC atomically accumulates on top)
__global__ void out_init_kernel(const float* __restrict__ fcb, float* __restrict__ out) {
    const int i = blockIdx.x * 1024 + threadIdx.x;
    out[i] = fcb[i % NC];
}

// ---------------------------------------------------------------------------
// FC round-5: out += hs * fcw^T. 2-term split (hs hi+lo exact-ish, fcw plain
// bf16). Block 256M x 128N, BK=32, kz=6 (480 blocks). A staged PACKED via
// global_load_lds with pre-swizzled global source (LDS dest linear, rule #21);
// unpacked to hi/lo at read. B (fcw) reg-staged fp32->bf16-hi. 80 KB LDS.
// ---------------------------------------------------------------------------
__global__ __launch_bounds__(512, 1) void fc5_kernel(
    const unsigned int* __restrict__ hs,  // [B][KF] packed
    const float* __restrict__ fcw,        // [600][KF]
    float* __restrict__ out)              // [B][600]
{
    __shared__ unsigned int  Apk[2][256 * 32];   // 32 KB each: packed (hi|lo), swizzled chunks
    __shared__ unsigned short Bs[2][128 * 32];   // 8 KB each: bf16 hi, swizzled chunks

    const int tid = threadIdx.x;
    const int m0 = blockIdx.x * 256;
    const int n0 = blockIdx.y * 128;
    const int k0 = blockIdx.z * 1280;            // 40 BK=32 tiles
    const int wave = tid >> 6, lane = tid & 63;
    const int wm = wave >> 1, wn = wave & 1;     // 4m x 2n waves, wave-tile 64x64
    const int l15 = lane & 15, lq = lane >> 4;

    f32x4 acc[4][4];
#pragma unroll
    for (int a = 0; a < 4; ++a)
#pragma unroll
        for (int b = 0; b < 4; ++b) acc[a][b] = (f32x4){0, 0, 0, 0};

    // A via global_load_lds: per wave 4 calls x 1KB; LDS linear, source pre-swizzled.
    // lane covers row (lane>>3) of the 8-row chunk, 16B-chunk (lane&7);
    // logical chunk fetched = (lane&7) ^ (row&7)  [inverse == forward XOR swizzle]
    const int ga_row = lane >> 3;
    const int ga_chk = (lane & 7) ^ ga_row;

#define STAGE_A(buf, kc_) do {                                                        \
    _Pragma("unroll")                                                                 \
    for (int c_ = 0; c_ < 4; ++c_) {                                                  \
        const int bc_ = wave * 4 + c_;                                                \
        const unsigned int* g_ = hs + (size_t)(m0 + bc_ * 8 + ga_row) * KF            \
                                    + (kc_) + (ga_chk << 2);                          \
        __builtin_amdgcn_global_load_lds((gas_u32)g_, (las_u32)&Apk[buf][bc_ * 256],  \
                                         16, 0, 0);                                   \
    }                                                                                 \
} while (0)

    // B staging: 128 rows x 32 floats = 2 float4 per thread
    float4 pb[2];
#define LOAD_B(kc_) do {                                                              \
    _Pragma("unroll")                                                                 \
    for (int it = 0; it < 2; ++it) {                                                  \
        const int g_ = tid + it * 512, row_ = g_ >> 3, qi_ = g_ & 7;                  \
        const int cc_ = n0 + row_;                                                    \
        pb[it] = (cc_ < NC) ? *(const float4*)(fcw + (size_t)cc_ * KF + (kc_) + qi_ * 4) \
                            : make_float4(0.f, 0.f, 0.f, 0.f);                        \
    }                                                                                 \
} while (0)

#define WRITE_B(buf) do {                                                             \
    _Pragma("unroll")                                                                 \
    for (int it = 0; it < 2; ++it) {                                                  \
        const int g_ = tid + it * 512, row_ = g_ >> 3, qi_ = g_ & 7;                  \
        const int ch_ = qi_ >> 1, hf_ = qi_ & 1;                                      \
        unsigned short* base_ = &Bs[buf][row_ * 32];                                  \
        const float bv_[4] = {pb[it].x, pb[it].y, pb[it].z, pb[it].w};                \
        unsigned short h4_[4];                                                        \
        _Pragma("unroll")                                                             \
        for (int e = 0; e < 4; ++e) h4_[e] = f2bf(bv_[e]);                            \
        uint2 wv_;                                                                    \
        wv_.x = (unsigned int)h4_[0] | ((unsigned int)h4_[1] << 16);                  \
        wv_.y = (unsigned int)h4_[2] | ((unsigned int)h4_[3] << 16);                  \
        *(uint2*)(base_ + ((ch_ ^ (row_ & 3)) << 3) + hf_ * 4) = wv_;                 \
    }                                                                                 \
} while (0)

#define MFMA_PHASE(buf) do {                                                          \
    bf16x8 aH_[4], aL_[4], bH_[4];                                                    \
    _Pragma("unroll")                                                                 \
    for (int t = 0; t < 4; ++t) {                                                     \
        const int mr_ = wm * 64 + t * 16 + l15;                                       \
        const unsigned int* pr_ = &Apk[buf][mr_ * 32];                                \
        const int q0_ = (2 * lq) ^ (mr_ & 7);                                         \
        const int q1_ = (2 * lq + 1) ^ (mr_ & 7);                                     \
        const uint4 c0_ = *(const uint4*)(pr_ + q0_ * 4);                             \
        const uint4 c1_ = *(const uint4*)(pr_ + q1_ * 4);                             \
        unpk(c0_, c1_, aH_[t], aL_[t]);                                               \
        const int nr_ = wn * 64 + t * 16 + l15;                                       \
        bH_[t] = *(const bf16x8*)(&Bs[buf][nr_ * 32] + ((lq ^ (nr_ & 3)) << 3));      \
    }                                                                                 \
    _Pragma("unroll")                                                                 \
    for (int mt = 0; mt < 4; ++mt)                                                    \
        _Pragma("unroll")                                                             \
        for (int nt = 0; nt < 4; ++nt) {                                              \
            acc[mt][nt] = MFMA16(aH_[mt], bH_[nt], acc[mt][nt]);                      \
            acc[mt][nt] = MFMA16(aL_[mt], bH_[nt], acc[mt][nt]);                      \
        }                                                                             \
} while (0)

    // prologue: tile 0
    STAGE_A(0, k0);
    LOAD_B(k0);
    asm volatile("s_waitcnt vmcnt(0)" ::: "memory");
    WRITE_B(0);
    asm volatile("s_waitcnt lgkmcnt(0)" ::: "memory");
    __builtin_amdgcn_s_barrier();
    __builtin_amdgcn_sched_barrier(0);

#pragma unroll 1
    for (int t = 0; t < 40; ++t) {
        const int cur = t & 1, nxt = cur ^ 1;
        const bool more = (t + 1) < 40;
        if (more) {
            STAGE_A(nxt, k0 + (t + 1) * 32);
            LOAD_B(k0 + (t + 1) * 32);
        }
        MFMA_PHASE(cur);
        asm volatile("s_waitcnt vmcnt(0)" ::: "memory");   // A-glds(nxt) + pb complete
        __builtin_amdgcn_sched_barrier(0);
        if (more) WRITE_B(nxt);
        asm volatile("s_waitcnt lgkmcnt(0)" ::: "memory");
        __builtin_amdgcn_s_barrier();
        __builtin_amdgcn_sched_barrier(0);
    }

    // epilogue: atomic accumulate (kz=6 chunks per out element)
#pragma unroll
    for (int mt = 0; mt < 4; ++mt) {
        const int row = m0 + wm * 64 + mt * 16 + lq * 4;
#pragma unroll
        for (int nt = 0; nt < 4; ++nt) {
            const int col = n0 + wn * 64 + nt * 16 + l15;
            if (col < NC) {
#pragma unroll
                for (int r = 0; r < 4; ++r)
                    atomicAdd(out + (size_t)(row + r) * NC + col, acc[mt][nt][r]);
            }
        }
    }
#undef STAGE_A
#undef LOAD_B
#undef WRITE_B
#undef MFMA_PHASE
}

extern "C" void kernel_launch(void* const* d_in, const int* in_sizes, int n_in,
                              void* d_out, int out_size, void* d_ws, size_t ws_size,
                              hipStream_t stream) {
    (void)in_sizes; (void)n_in; (void)out_size;
    const float* x    = (const float*)d_in[0];
    const float* w_ih = (const float*)d_in[1];
    const float* w_hh = (const float*)d_in[2];
    const float* b_ih = (const float*)d_in[3];
    const float* b_hh = (const float*)d_in[4];
    const float* fcw  = (const float*)d_in[5];
    const float* fcb  = (const float*)d_in[6];
    float* out = (float*)d_out;
    unsigned int* hs = (unsigned int*)d_ws;          // [B][KF] packed bf16 hi/lo = 125.8 MB

    if (ws_size < (size_t)KF * BB * sizeof(unsigned int)) return;

    out_init_kernel<<<dim3((BB * NC) / 1024), 1024, 0, stream>>>(fcb, out);
    gru5_kernel<<<dim3(BB / 16, 2), 256, 0, stream>>>(x, w_ih, w_hh, b_ih, b_hh, hs);
    fc5_kernel<<<dim3(BB / 256, 5, 6), 512, 0, stream>>>(hs, fcw, out);
}